// Round 1
// 424.789 us; speedup vs baseline: 1.1678x; 1.1678x over previous
//
#include <hip/hip_runtime.h>
#include <math.h>

#define IMH 512
#define IMW 512
#define NIMG 64
#define NPIX (IMH*IMW)
#define NELEM (NPIX*3)
#define CXF 255.5f
#define CYF 255.5f
#define ENHF 1.45f
#define INVENHF (1.0f/1.45f)
#define FILLF 0.5f
#define MBPI0 64     // reduction blocks per image (raw-input mean)
#define MBPI1 512    // reduction blocks per image (layer-0-output mean) - latency fix
#define TW 32        // output tile width per block
#define TH 32        // output tile height per block
// worst case staged bbox: rotate 15deg on 32x32 tile: span 31*(cos+sin)=37.97 -> bw,bh <= 42
#define MAXLDS 1800  // 42*42 = 1764 staged pixels max, +margin

struct F3 { float x, y, z; };

__device__ __forceinline__ F3 mk3(float v){ F3 r; r.x=v; r.y=v; r.z=v; return r; }

__device__ __forceinline__ F3 ldpix(const float* __restrict__ im, int y, int x){
  const float* p = im + (y*IMW + x)*3;
  F3 r; r.x=p[0]; r.y=p[1]; r.z=p[2]; return r;
}

__device__ __forceinline__ F3 clip01(F3 v){
  F3 r;
  r.x = fminf(fmaxf(v.x, 0.f), 1.f);
  r.y = fminf(fmaxf(v.y, 0.f), 1.f);
  r.z = fminf(fmaxf(v.z, 0.f), 1.f);
  return r;
}

// inverse-affine coefficients for ops 0..4 (rotate, shear_x, shear_y, trans_x, trans_y)
__device__ __forceinline__ void affine_params(int op, float s,
    float& a, float& b, float& tx, float& c, float& d, float& ty){
  a = 1.f; b = 0.f; tx = 0.f; c = 0.f; d = 1.f; ty = 0.f;
  if (op == 0){            // rotate by s*15deg: cos even, sin odd -> fold sign
    a = 0.96592582628907f; b = s * 0.25881904510252f; c = -b; d = a;
  } else if (op == 1){     // shear_x
    b = -s * 0.15f;
  } else if (op == 2){     // shear_y
    c = -s * 0.15f;
  } else if (op == 3){     // trans_x: t = s*0.15*512
    tx = -s * 76.8f;
  } else if (op == 4){     // trans_y
    ty = -s * 76.8f;
  }
}

// bilinear sample of the RAW input image with FILL for out-of-bounds corners.
// Fast path (all 4 corners interior): two merged 6-float row loads, no branches.
__device__ __forceinline__ F3 bilin_img(const float* __restrict__ im, float xi, float yi){
  float x0f = floorf(xi), y0f = floorf(yi);
  float wx = xi - x0f, wy = yi - y0f;
  float w00 = (1.f-wx)*(1.f-wy), w01 = wx*(1.f-wy);
  float w10 = (1.f-wx)*wy,       w11 = wx*wy;
  int x0 = (int)x0f, y0 = (int)y0f;
  F3 r;
  if (x0 >= 0 && y0 >= 0 && x0 < IMW-1 && y0 < IMH-1){
    const float* p0 = im + (y0*IMW + x0)*3;
    const float* p1 = p0 + IMW*3;
    r.x = w00*p0[0] + w01*p0[3] + w10*p1[0] + w11*p1[3];
    r.y = w00*p0[1] + w01*p0[4] + w10*p1[1] + w11*p1[4];
    r.z = w00*p0[2] + w01*p0[5] + w10*p1[2] + w11*p1[5];
  } else {
    r = mk3(0.f);
    #pragma unroll
    for (int cidx = 0; cidx < 4; cidx++){
      int dx = cidx & 1, dy = cidx >> 1;
      int xx = x0 + dx, yy = y0 + dy;
      float w = (dx ? wx : (1.f - wx)) * (dy ? wy : (1.f - wy));
      F3 v;
      if (xx >= 0 && xx < IMW && yy >= 0 && yy < IMH)
        v = ldpix(im, yy, xx);
      else
        v = mk3(FILLF);
      r.x += w * v.x; r.y += w * v.y; r.z += w * v.z;
    }
  }
  return r;
}

// value of the layer-0 output at integer pixel (x,y), computed on the fly
__device__ F3 eval0(const float* __restrict__ im, int op, float s, float mean0, int x, int y){
  if (op < 5){
    float a,b,tx,c,d,ty; affine_params(op, s, a, b, tx, c, d, ty);
    float fx = (float)x - CXF, fy = (float)y - CYF;
    return bilin_img(im, a*fx + b*fy + tx + CXF, c*fx + d*fy + ty + CYF);
  }
  F3 v = ldpix(im, y, x);
  float f = (s > 0.f) ? ENHF : INVENHF;
  if (op == 5){           // brightness: clip(f * img)
    F3 r; r.x = f*v.x; r.y = f*v.y; r.z = f*v.z; return clip01(r);
  }
  if (op == 6){           // contrast: clip(mean + f*(img-mean))
    F3 r;
    r.x = mean0 + f*(v.x - mean0);
    r.y = mean0 + f*(v.y - mean0);
    r.z = mean0 + f*(v.z - mean0);
    return clip01(r);
  }
  // sharpness: clip(smooth + f*(img - smooth)), 3x3 kernel [[1,1,1],[1,5,1],[1,1,1]]/13, edge pad
  F3 sm; sm.x = (5.f/13.f)*v.x; sm.y = (5.f/13.f)*v.y; sm.z = (5.f/13.f)*v.z;
  #pragma unroll
  for (int dy = -1; dy <= 1; dy++){
    #pragma unroll
    for (int dx = -1; dx <= 1; dx++){
      if (dx == 0 && dy == 0) continue;
      int yy = min(max(y + dy, 0), IMH-1);
      int xx = min(max(x + dx, 0), IMW-1);
      F3 q = ldpix(im, yy, xx);
      sm.x += (1.f/13.f)*q.x; sm.y += (1.f/13.f)*q.y; sm.z += (1.f/13.f)*q.z;
    }
  }
  F3 r;
  r.x = sm.x + f*(v.x - sm.x);
  r.y = sm.y + f*(v.y - sm.y);
  r.z = sm.z + f*(v.z - sm.z);
  return clip01(r);
}

__device__ __forceinline__ float block_reduce(float v){
  #pragma unroll
  for (int off = 32; off > 0; off >>= 1) v += __shfl_down(v, off, 64);
  __shared__ float sm[4];
  int lane = threadIdx.x & 63, wid = threadIdx.x >> 6;
  if (lane == 0) sm[wid] = v;
  __syncthreads();
  float r = 0.f;
  if (threadIdx.x == 0) r = sm[0] + sm[1] + sm[2] + sm[3];
  return r;
}

// mean of raw input image (only for images whose layer-0 op is contrast)
__global__ __launch_bounds__(256) void mean0_kernel(const float* __restrict__ images,
    const int* __restrict__ ops, float* __restrict__ means){
  int img = blockIdx.x / MBPI0;
  if (ops[2*img] != 6) return;
  const float4* im = (const float4*)(images + (size_t)img * NELEM);
  float s = 0.f;
  for (int i = (blockIdx.x % MBPI0)*256 + threadIdx.x; i < NELEM/4; i += MBPI0*256){
    float4 v = im[i];
    s += v.x + v.y + v.z + v.w;
  }
  s = block_reduce(s);
  if (threadIdx.x == 0) atomicAdd(&means[2*img], s * (1.0f/(float)NELEM));
}

// mean of layer-0 output (only for images whose layer-1 op is contrast).
// MBPI1=512 so the ~8 active images spread over ~4096 blocks (16/CU) instead of 2/CU.
__global__ __launch_bounds__(256) void mean1_kernel(const float* __restrict__ images,
    const int* __restrict__ ops, const int* __restrict__ signs, float* __restrict__ means){
  int img = blockIdx.x / MBPI1;
  if (ops[2*img + 1] != 6) return;
  int op0 = ops[2*img];
  float s0 = signs[2*img] ? 1.f : -1.f;
  float mean0 = means[2*img];
  const float* im = images + (size_t)img * NELEM;
  float s = 0.f;
  for (int p = (blockIdx.x % MBPI1)*256 + threadIdx.x; p < NPIX; p += MBPI1*256){
    F3 v = eval0(im, op0, s0, mean0, p & (IMW-1), p >> 9);
    s += v.x + v.y + v.z;
  }
  s = block_reduce(s);
  if (threadIdx.x == 0) atomicAdd(&means[2*img + 1], s * (1.0f/(float)NELEM));
}

// packed coalesced store: 4 px = 12 floats = 3 float4 (48B-aligned base)
__device__ __forceinline__ void store4(float* __restrict__ out, int img, int y, int xbase,
                                       const F3* res){
  float4 o0 = make_float4(res[0].x, res[0].y, res[0].z, res[1].x);
  float4 o1 = make_float4(res[1].y, res[1].z, res[2].x, res[2].y);
  float4 o2 = make_float4(res[2].z, res[3].x, res[3].y, res[3].z);
  float4* op = (float4*)(out + ((size_t)img * NPIX + (size_t)y * IMW + xbase) * 3);
  op[0] = o0; op[1] = o1; op[2] = o2;
}

// Tiled fused kernel: 32x32 tiles (square minimizes rotate bbox -> 21.6KB LDS, 7 blocks/CU).
// Pointwise layer-1 ops skip LDS entirely (no reuse to exploit).
__global__ __launch_bounds__(256) void apply_kernel(const float* __restrict__ images,
    const int* __restrict__ ops, const int* __restrict__ signs,
    const float* __restrict__ means, float* __restrict__ out){
  int img  = blockIdx.x >> 8;            // 256 tiles per image (16 x 16)
  int tile = blockIdx.x & 255;
  int tx0 = (tile & 15) * TW;
  int ty0 = (tile >> 4) * TH;
  const float* im = images + (size_t)img * NELEM;
  int op0 = ops[2*img], op1 = ops[2*img + 1];
  float s0 = signs[2*img]     ? 1.f : -1.f;
  float s1 = signs[2*img + 1] ? 1.f : -1.f;
  float mean0 = means[2*img], mean1 = means[2*img + 1];

  int row   = threadIdx.x >> 3;                 // 0..31
  int xbase = tx0 + ((threadIdx.x & 7) << 2);   // 4 consecutive px per thread
  int y     = ty0 + row;
  float f1 = (s1 > 0.f) ? ENHF : INVENHF;

  // ---- pointwise layer-1: one eval0 per output px, no reuse -> no LDS round-trip ----
  if (op1 == 5 || op1 == 6){
    F3 res[4];
    #pragma unroll
    for (int q = 0; q < 4; q++){
      F3 v = eval0(im, op0, s0, mean0, xbase + q, y);
      F3 o;
      if (op1 == 5){
        o.x = f1*v.x; o.y = f1*v.y; o.z = f1*v.z;
      } else {
        o.x = mean1 + f1*(v.x - mean1);
        o.y = mean1 + f1*(v.y - mean1);
        o.z = mean1 + f1*(v.z - mean1);
      }
      res[q] = clip01(o);
    }
    store4(out, img, y, xbase, res);
    return;
  }

  // ---- bbox of layer-0 pixels needed by this tile's layer-1 op ----
  float a1=1.f,b1=0.f,txx=0.f,c1=0.f,d1=1.f,tyy=0.f;
  int bx0, by0, bx1, by1;
  if (op1 < 5){
    affine_params(op1, s1, a1, b1, txx, c1, d1, tyy);
    float xmin = 1e30f, xmax = -1e30f, ymin = 1e30f, ymax = -1e30f;
    #pragma unroll
    for (int i = 0; i < 4; i++){
      float fx = (float)(tx0 + (i & 1) * (TW - 1)) - CXF;
      float fy = (float)(ty0 + (i >> 1) * (TH - 1)) - CYF;
      float xi = a1*fx + b1*fy + txx + CXF;
      float yi = c1*fx + d1*fy + tyy + CYF;
      xmin = fminf(xmin, xi); xmax = fmaxf(xmax, xi);
      ymin = fminf(ymin, yi); ymax = fmaxf(ymax, yi);
    }
    bx0 = (int)floorf(xmin) - 1; bx1 = (int)floorf(xmax) + 2;
    by0 = (int)floorf(ymin) - 1; by1 = (int)floorf(ymax) + 2;
  } else {                               // sharpness needs +-1 halo
    bx0 = tx0 - 1; bx1 = tx0 + TW; by0 = ty0 - 1; by1 = ty0 + TH;
  }
  bx0 = max(bx0, 0); by0 = max(by0, 0);
  bx1 = min(bx1, IMW - 1); by1 = min(by1, IMH - 1);
  int bw = bx1 - bx0 + 1, bh = by1 - by0 + 1;
  int nstage = (bw > 0 && bh > 0) ? bw * bh : 0;

  // ---- stage eval0 over bbox into LDS (each layer-0 pixel computed ONCE) ----
  __shared__ float lds[MAXLDS * 3];
  for (int idx = threadIdx.x; idx < nstage; idx += 256){
    int iy = idx / bw;
    int ix = idx - iy * bw;
    F3 v = eval0(im, op0, s0, mean0, bx0 + ix, by0 + iy);
    lds[idx*3 + 0] = v.x; lds[idx*3 + 1] = v.y; lds[idx*3 + 2] = v.z;
  }
  __syncthreads();

  // ---- layer-1 from LDS ----
  F3 res[4];
  #pragma unroll
  for (int q = 0; q < 4; q++){
    int x = xbase + q;
    F3 o;
    if (op1 < 5){
      float fx = (float)x - CXF, fy = (float)y - CYF;
      float xi = a1*fx + b1*fy + txx + CXF;
      float yi = c1*fx + d1*fy + tyy + CYF;
      float xf0 = floorf(xi), yf0 = floorf(yi);
      float wx = xi - xf0, wy = yi - yf0;
      float w00 = (1.f-wx)*(1.f-wy), w01 = wx*(1.f-wy);
      float w10 = (1.f-wx)*wy,       w11 = wx*wy;
      int x0 = (int)xf0, y0 = (int)yf0;
      if (x0 >= 0 && y0 >= 0 && x0 < IMW-1 && y0 < IMH-1){
        // interior fast path: corners guaranteed staged (bbox covers tile footprint)
        const float* q0 = lds + ((y0 - by0) * bw + (x0 - bx0)) * 3;
        const float* q1 = q0 + bw * 3;
        o.x = w00*q0[0] + w01*q0[3] + w10*q1[0] + w11*q1[3];
        o.y = w00*q0[1] + w01*q0[4] + w10*q1[1] + w11*q1[4];
        o.z = w00*q0[2] + w01*q0[5] + w10*q1[2] + w11*q1[5];
      } else {
        o = mk3(0.f);
        #pragma unroll
        for (int ci = 0; ci < 4; ci++){
          int dx = ci & 1, dy = ci >> 1;
          int xx = x0 + dx, yy = y0 + dy;
          float w = (dx ? wx : (1.f - wx)) * (dy ? wy : (1.f - wy));
          F3 v;
          if (xx >= 0 && xx < IMW && yy >= 0 && yy < IMH){
            int li = ((yy - by0) * bw + (xx - bx0)) * 3;
            v.x = lds[li]; v.y = lds[li+1]; v.z = lds[li+2];
          } else v = mk3(FILLF);
          o.x += w * v.x; o.y += w * v.y; o.z += w * v.z;
        }
      }
    } else {  // sharpness over layer-0 output, taps from LDS (edge-clamped)
      int li0 = ((y - by0) * bw + (x - bx0)) * 3;
      F3 v; v.x = lds[li0]; v.y = lds[li0+1]; v.z = lds[li0+2];
      F3 sm; sm.x = (5.f/13.f)*v.x; sm.y = (5.f/13.f)*v.y; sm.z = (5.f/13.f)*v.z;
      #pragma unroll
      for (int dy = -1; dy <= 1; dy++){
        #pragma unroll
        for (int dx = -1; dx <= 1; dx++){
          if (dx == 0 && dy == 0) continue;
          int yy = min(max(y + dy, 0), IMH-1);
          int xx = min(max(x + dx, 0), IMW-1);
          int li = ((yy - by0) * bw + (xx - bx0)) * 3;
          sm.x += (1.f/13.f)*lds[li];
          sm.y += (1.f/13.f)*lds[li+1];
          sm.z += (1.f/13.f)*lds[li+2];
        }
      }
      o.x = sm.x + f1*(v.x - sm.x);
      o.y = sm.y + f1*(v.y - sm.y);
      o.z = sm.z + f1*(v.z - sm.z);
    }
    res[q] = clip01(o);
  }

  store4(out, img, y, xbase, res);
}

extern "C" void kernel_launch(void* const* d_in, const int* in_sizes, int n_in,
                              void* d_out, int out_size, void* d_ws, size_t ws_size,
                              hipStream_t stream){
  const float* images = (const float*)d_in[0];
  const int*   ops    = (const int*)d_in[1];
  const int*   signs  = (const int*)d_in[2];
  float* out   = (float*)d_out;
  float* means = (float*)d_ws;   // 2 floats per image: [mean0, mean1]

  hipMemsetAsync(means, 0, 2*NIMG*sizeof(float), stream);
  mean0_kernel<<<NIMG*MBPI0, 256, 0, stream>>>(images, ops, means);
  mean1_kernel<<<NIMG*MBPI1, 256, 0, stream>>>(images, ops, signs, means);
  apply_kernel<<<NIMG*256, 256, 0, stream>>>(images, ops, signs, means, out);
}

// Round 2
// 409.396 us; speedup vs baseline: 1.2117x; 1.0376x over previous
//
#include <hip/hip_runtime.h>
#include <math.h>

#define IMH 512
#define IMW 512
#define NIMG 64
#define NPIX (IMH*IMW)
#define NELEM (NPIX*3)
#define CXF 255.5f
#define CYF 255.5f
#define ENHF 1.45f
#define INVENHF (1.0f/1.45f)
#define FILLF 0.5f
#define MBPI0 64     // reduction blocks per image (raw-input mean)
#define TW 32        // output tile width per block
#define TH 32        // output tile height per block
// worst case staged bbox: rotate 15deg on 32x32 tile: span 31*(cos+sin)=37.97 -> bw,bh <= 42
#define MAXLDS 1800  // 42*42 = 1764 staged pixels max, +margin

struct F3 { float x, y, z; };

__device__ __forceinline__ F3 mk3(float v){ F3 r; r.x=v; r.y=v; r.z=v; return r; }

__device__ __forceinline__ F3 ldpix(const float* __restrict__ im, int y, int x){
  const float* p = im + (y*IMW + x)*3;
  F3 r; r.x=p[0]; r.y=p[1]; r.z=p[2]; return r;
}

__device__ __forceinline__ F3 clip01(F3 v){
  F3 r;
  r.x = fminf(fmaxf(v.x, 0.f), 1.f);
  r.y = fminf(fmaxf(v.y, 0.f), 1.f);
  r.z = fminf(fmaxf(v.z, 0.f), 1.f);
  return r;
}

// inverse-affine coefficients for ops 0..4 (rotate, shear_x, shear_y, trans_x, trans_y)
__device__ __forceinline__ void affine_params(int op, float s,
    float& a, float& b, float& tx, float& c, float& d, float& ty){
  a = 1.f; b = 0.f; tx = 0.f; c = 0.f; d = 1.f; ty = 0.f;
  if (op == 0){            // rotate by s*15deg: cos even, sin odd -> fold sign
    a = 0.96592582628907f; b = s * 0.25881904510252f; c = -b; d = a;
  } else if (op == 1){     // shear_x
    b = -s * 0.15f;
  } else if (op == 2){     // shear_y
    c = -s * 0.15f;
  } else if (op == 3){     // trans_x: t = s*0.15*512
    tx = -s * 76.8f;
  } else if (op == 4){     // trans_y
    ty = -s * 76.8f;
  }
}

// bilinear sample of the RAW input image with FILL for out-of-bounds corners.
// Fast path (all 4 corners interior): two merged 6-float row loads, no branches.
__device__ __forceinline__ F3 bilin_img(const float* __restrict__ im, float xi, float yi){
  float x0f = floorf(xi), y0f = floorf(yi);
  float wx = xi - x0f, wy = yi - y0f;
  float w00 = (1.f-wx)*(1.f-wy), w01 = wx*(1.f-wy);
  float w10 = (1.f-wx)*wy,       w11 = wx*wy;
  int x0 = (int)x0f, y0 = (int)y0f;
  F3 r;
  if (x0 >= 0 && y0 >= 0 && x0 < IMW-1 && y0 < IMH-1){
    const float* p0 = im + (y0*IMW + x0)*3;
    const float* p1 = p0 + IMW*3;
    r.x = w00*p0[0] + w01*p0[3] + w10*p1[0] + w11*p1[3];
    r.y = w00*p0[1] + w01*p0[4] + w10*p1[1] + w11*p1[4];
    r.z = w00*p0[2] + w01*p0[5] + w10*p1[2] + w11*p1[5];
  } else {
    r = mk3(0.f);
    #pragma unroll
    for (int cidx = 0; cidx < 4; cidx++){
      int dx = cidx & 1, dy = cidx >> 1;
      int xx = x0 + dx, yy = y0 + dy;
      float w = (dx ? wx : (1.f - wx)) * (dy ? wy : (1.f - wy));
      F3 v;
      if (xx >= 0 && xx < IMW && yy >= 0 && yy < IMH)
        v = ldpix(im, yy, xx);
      else
        v = mk3(FILLF);
      r.x += w * v.x; r.y += w * v.y; r.z += w * v.z;
    }
  }
  return r;
}

// value of the layer-0 output at integer pixel (x,y), computed on the fly
__device__ F3 eval0(const float* __restrict__ im, int op, float s, float mean0, int x, int y){
  if (op < 5){
    float a,b,tx,c,d,ty; affine_params(op, s, a, b, tx, c, d, ty);
    float fx = (float)x - CXF, fy = (float)y - CYF;
    return bilin_img(im, a*fx + b*fy + tx + CXF, c*fx + d*fy + ty + CYF);
  }
  F3 v = ldpix(im, y, x);
  float f = (s > 0.f) ? ENHF : INVENHF;
  if (op == 5){           // brightness: clip(f * img)
    F3 r; r.x = f*v.x; r.y = f*v.y; r.z = f*v.z; return clip01(r);
  }
  if (op == 6){           // contrast: clip(mean + f*(img-mean))
    F3 r;
    r.x = mean0 + f*(v.x - mean0);
    r.y = mean0 + f*(v.y - mean0);
    r.z = mean0 + f*(v.z - mean0);
    return clip01(r);
  }
  // sharpness: clip(smooth + f*(img - smooth)), 3x3 kernel [[1,1,1],[1,5,1],[1,1,1]]/13, edge pad
  F3 sm; sm.x = (5.f/13.f)*v.x; sm.y = (5.f/13.f)*v.y; sm.z = (5.f/13.f)*v.z;
  #pragma unroll
  for (int dy = -1; dy <= 1; dy++){
    #pragma unroll
    for (int dx = -1; dx <= 1; dx++){
      if (dx == 0 && dy == 0) continue;
      int yy = min(max(y + dy, 0), IMH-1);
      int xx = min(max(x + dx, 0), IMW-1);
      F3 q = ldpix(im, yy, xx);
      sm.x += (1.f/13.f)*q.x; sm.y += (1.f/13.f)*q.y; sm.z += (1.f/13.f)*q.z;
    }
  }
  F3 r;
  r.x = sm.x + f*(v.x - sm.x);
  r.y = sm.y + f*(v.y - sm.y);
  r.z = sm.z + f*(v.z - sm.z);
  return clip01(r);
}

__device__ __forceinline__ float block_reduce(float v){
  #pragma unroll
  for (int off = 32; off > 0; off >>= 1) v += __shfl_down(v, off, 64);
  __shared__ float sm[4];
  int lane = threadIdx.x & 63, wid = threadIdx.x >> 6;
  if (lane == 0) sm[wid] = v;
  __syncthreads();
  float r = 0.f;
  if (threadIdx.x == 0) r = sm[0] + sm[1] + sm[2] + sm[3];
  return r;
}

// mean of raw input image (only for images whose layer-0 op is contrast)
__global__ __launch_bounds__(256) void mean0_kernel(const float* __restrict__ images,
    const int* __restrict__ ops, float* __restrict__ means){
  int img = blockIdx.x / MBPI0;
  if (ops[2*img] != 6) return;
  const float4* im = (const float4*)(images + (size_t)img * NELEM);
  float s = 0.f;
  for (int i = (blockIdx.x % MBPI0)*256 + threadIdx.x; i < NELEM/4; i += MBPI0*256){
    float4 v = im[i];
    s += v.x + v.y + v.z + v.w;
  }
  s = block_reduce(s);
  if (threadIdx.x == 0) atomicAdd(&means[2*img], s * (1.0f/(float)NELEM));
}

// packed coalesced store: 4 px = 12 floats = 3 float4 (48B-aligned base)
__device__ __forceinline__ void store4(float* __restrict__ out, int img, int y, int xbase,
                                       const F3* res){
  float4 o0 = make_float4(res[0].x, res[0].y, res[0].z, res[1].x);
  float4 o1 = make_float4(res[1].y, res[1].z, res[2].x, res[2].y);
  float4 o2 = make_float4(res[2].z, res[3].x, res[3].y, res[3].z);
  float4* op = (float4*)(out + ((size_t)img * NPIX + (size_t)y * IMW + xbase) * 3);
  op[0] = o0; op[1] = o1; op[2] = o2;
}

// Tiled fused kernel: 32x32 tiles (21.6KB LDS). Pointwise layer-1 ops skip LDS.
// Contrast layer-1 (op1==6): write L0 to out + accumulate its mean; fixup_kernel
// finishes the (pointwise, invertible-order) contrast transform in place. This
// deletes the entire duplicate-eval0 mean1 pass.
__global__ __launch_bounds__(256) void apply_kernel(const float* __restrict__ images,
    const int* __restrict__ ops, const int* __restrict__ signs,
    float* __restrict__ means, float* __restrict__ out){
  int img  = blockIdx.x >> 8;            // 256 tiles per image (16 x 16)
  int tile = blockIdx.x & 255;
  int tx0 = (tile & 15) * TW;
  int ty0 = (tile >> 4) * TH;
  const float* im = images + (size_t)img * NELEM;
  int op0 = ops[2*img], op1 = ops[2*img + 1];
  float s0 = signs[2*img]     ? 1.f : -1.f;
  float s1 = signs[2*img + 1] ? 1.f : -1.f;
  float mean0 = means[2*img];

  int row   = threadIdx.x >> 3;                 // 0..31
  int xbase = tx0 + ((threadIdx.x & 7) << 2);   // 4 consecutive px per thread
  int y     = ty0 + row;
  float f1 = (s1 > 0.f) ? ENHF : INVENHF;

  // ---- pointwise layer-1: one eval0 per output px, no reuse -> no LDS round-trip ----
  if (op1 == 5 || op1 == 6){
    F3 res[4];
    float ssum = 0.f;
    #pragma unroll
    for (int q = 0; q < 4; q++){
      F3 v = eval0(im, op0, s0, mean0, xbase + q, y);
      if (op1 == 5){
        F3 o; o.x = f1*v.x; o.y = f1*v.y; o.z = f1*v.z;
        res[q] = clip01(o);
      } else {
        res[q] = v;                       // write raw L0; fixup applies contrast
        ssum += v.x + v.y + v.z;
      }
    }
    store4(out, img, y, xbase, res);
    if (op1 == 6){
      ssum = block_reduce(ssum);
      if (threadIdx.x == 0) atomicAdd(&means[2*img + 1], ssum * (1.0f/(float)NELEM));
    }
    return;
  }

  // ---- bbox of layer-0 pixels needed by this tile's layer-1 op ----
  float a1=1.f,b1=0.f,txx=0.f,c1=0.f,d1=1.f,tyy=0.f;
  int bx0, by0, bx1, by1;
  if (op1 < 5){
    affine_params(op1, s1, a1, b1, txx, c1, d1, tyy);
    float xmin = 1e30f, xmax = -1e30f, ymin = 1e30f, ymax = -1e30f;
    #pragma unroll
    for (int i = 0; i < 4; i++){
      float fx = (float)(tx0 + (i & 1) * (TW - 1)) - CXF;
      float fy = (float)(ty0 + (i >> 1) * (TH - 1)) - CYF;
      float xi = a1*fx + b1*fy + txx + CXF;
      float yi = c1*fx + d1*fy + tyy + CYF;
      xmin = fminf(xmin, xi); xmax = fmaxf(xmax, xi);
      ymin = fminf(ymin, yi); ymax = fmaxf(ymax, yi);
    }
    bx0 = (int)floorf(xmin) - 1; bx1 = (int)floorf(xmax) + 2;
    by0 = (int)floorf(ymin) - 1; by1 = (int)floorf(ymax) + 2;
  } else {                               // sharpness needs +-1 halo
    bx0 = tx0 - 1; bx1 = tx0 + TW; by0 = ty0 - 1; by1 = ty0 + TH;
  }
  bx0 = max(bx0, 0); by0 = max(by0, 0);
  bx1 = min(bx1, IMW - 1); by1 = min(by1, IMH - 1);
  int bw = bx1 - bx0 + 1, bh = by1 - by0 + 1;
  int nstage = (bw > 0 && bh > 0) ? bw * bh : 0;

  // ---- stage eval0 over bbox into LDS (each layer-0 pixel computed ONCE) ----
  __shared__ float lds[MAXLDS * 3];
  for (int idx = threadIdx.x; idx < nstage; idx += 256){
    int iy = idx / bw;
    int ix = idx - iy * bw;
    F3 v = eval0(im, op0, s0, mean0, bx0 + ix, by0 + iy);
    lds[idx*3 + 0] = v.x; lds[idx*3 + 1] = v.y; lds[idx*3 + 2] = v.z;
  }
  __syncthreads();

  // ---- layer-1 from LDS ----
  F3 res[4];
  #pragma unroll
  for (int q = 0; q < 4; q++){
    int x = xbase + q;
    F3 o;
    if (op1 < 5){
      float fx = (float)x - CXF, fy = (float)y - CYF;
      float xi = a1*fx + b1*fy + txx + CXF;
      float yi = c1*fx + d1*fy + tyy + CYF;
      float xf0 = floorf(xi), yf0 = floorf(yi);
      float wx = xi - xf0, wy = yi - yf0;
      float w00 = (1.f-wx)*(1.f-wy), w01 = wx*(1.f-wy);
      float w10 = (1.f-wx)*wy,       w11 = wx*wy;
      int x0 = (int)xf0, y0 = (int)yf0;
      if (x0 >= 0 && y0 >= 0 && x0 < IMW-1 && y0 < IMH-1){
        // interior fast path: corners guaranteed staged (bbox covers tile footprint)
        const float* q0 = lds + ((y0 - by0) * bw + (x0 - bx0)) * 3;
        const float* q1 = q0 + bw * 3;
        o.x = w00*q0[0] + w01*q0[3] + w10*q1[0] + w11*q1[3];
        o.y = w00*q0[1] + w01*q0[4] + w10*q1[1] + w11*q1[4];
        o.z = w00*q0[2] + w01*q0[5] + w10*q1[2] + w11*q1[5];
      } else {
        o = mk3(0.f);
        #pragma unroll
        for (int ci = 0; ci < 4; ci++){
          int dx = ci & 1, dy = ci >> 1;
          int xx = x0 + dx, yy = y0 + dy;
          float w = (dx ? wx : (1.f - wx)) * (dy ? wy : (1.f - wy));
          F3 v;
          if (xx >= 0 && xx < IMW && yy >= 0 && yy < IMH){
            int li = ((yy - by0) * bw + (xx - bx0)) * 3;
            v.x = lds[li]; v.y = lds[li+1]; v.z = lds[li+2];
          } else v = mk3(FILLF);
          o.x += w * v.x; o.y += w * v.y; o.z += w * v.z;
        }
      }
    } else {  // sharpness over layer-0 output, taps from LDS (edge-clamped)
      int li0 = ((y - by0) * bw + (x - bx0)) * 3;
      F3 v; v.x = lds[li0]; v.y = lds[li0+1]; v.z = lds[li0+2];
      F3 sm; sm.x = (5.f/13.f)*v.x; sm.y = (5.f/13.f)*v.y; sm.z = (5.f/13.f)*v.z;
      #pragma unroll
      for (int dy = -1; dy <= 1; dy++){
        #pragma unroll
        for (int dx = -1; dx <= 1; dx++){
          if (dx == 0 && dy == 0) continue;
          int yy = min(max(y + dy, 0), IMH-1);
          int xx = min(max(x + dx, 0), IMW-1);
          int li = ((yy - by0) * bw + (xx - bx0)) * 3;
          sm.x += (1.f/13.f)*lds[li];
          sm.y += (1.f/13.f)*lds[li+1];
          sm.z += (1.f/13.f)*lds[li+2];
        }
      }
      o.x = sm.x + f1*(v.x - sm.x);
      o.y = sm.y + f1*(v.y - sm.y);
      o.z = sm.z + f1*(v.z - sm.z);
    }
    res[q] = clip01(o);
  }

  store4(out, img, y, xbase, res);
}

// In-place contrast finish for images with op1==6: out = clip(m1 + f*(L0 - m1)).
// Pure streaming, float4, ~24MB per active image -> ~10us total.
__global__ __launch_bounds__(256) void fixup_kernel(const int* __restrict__ ops,
    const int* __restrict__ signs, const float* __restrict__ means,
    float* __restrict__ out){
  int img = blockIdx.x >> 8;             // 256 blocks per image
  if (ops[2*img + 1] != 6) return;
  float f = signs[2*img + 1] ? ENHF : INVENHF;
  float m = means[2*img + 1];
  float4* p = (float4*)(out + (size_t)img * NELEM);
  const int n = NELEM / 4;               // 196608, divisible by 4
  for (int i = (blockIdx.x & 255)*256 + threadIdx.x; i < n; i += 256*256){
    float4 v = p[i];
    v.x = fminf(fmaxf(m + f*(v.x - m), 0.f), 1.f);
    v.y = fminf(fmaxf(m + f*(v.y - m), 0.f), 1.f);
    v.z = fminf(fmaxf(m + f*(v.z - m), 0.f), 1.f);
    v.w = fminf(fmaxf(m + f*(v.w - m), 0.f), 1.f);
    p[i] = v;
  }
}

extern "C" void kernel_launch(void* const* d_in, const int* in_sizes, int n_in,
                              void* d_out, int out_size, void* d_ws, size_t ws_size,
                              hipStream_t stream){
  const float* images = (const float*)d_in[0];
  const int*   ops    = (const int*)d_in[1];
  const int*   signs  = (const int*)d_in[2];
  float* out   = (float*)d_out;
  float* means = (float*)d_ws;   // 2 floats per image: [mean0, mean1]

  hipMemsetAsync(means, 0, 2*NIMG*sizeof(float), stream);
  mean0_kernel<<<NIMG*MBPI0, 256, 0, stream>>>(images, ops, means);
  apply_kernel<<<NIMG*256, 256, 0, stream>>>(images, ops, signs, means, out);
  fixup_kernel<<<NIMG*256, 256, 0, stream>>>(ops, signs, means, out);
}

// Round 3
// 401.172 us; speedup vs baseline: 1.2366x; 1.0205x over previous
//
#include <hip/hip_runtime.h>
#include <math.h>

#define IMH 512
#define IMW 512
#define NIMG 64
#define NPIX (IMH*IMW)
#define NELEM (NPIX*3)
#define CXF 255.5f
#define CYF 255.5f
#define ENHF 1.45f
#define INVENHF (1.0f/1.45f)
#define FILLF 0.5f
#define MBPI0 64     // reduction blocks per image (raw-input mean)
#define TW 32        // output tile width per block
#define TH 32        // output tile height per block
// tight bilinear support: rotate 15deg on 32x32 tile spans 31*1.2247=37.97
// -> floor range <= 38 -> bw,bh <= 40 -> 1600 px. 1700*12B = 20400B -> 8 blocks/CU.
#define MAXLDS 1700

struct F3 { float x, y, z; };

__device__ __forceinline__ F3 mk3(float v){ F3 r; r.x=v; r.y=v; r.z=v; return r; }

__device__ __forceinline__ F3 ldpix(const float* __restrict__ im, int y, int x){
  const float* p = im + (y*IMW + x)*3;
  F3 r; r.x=p[0]; r.y=p[1]; r.z=p[2]; return r;
}

__device__ __forceinline__ F3 clip01(F3 v){
  F3 r;
  r.x = fminf(fmaxf(v.x, 0.f), 1.f);
  r.y = fminf(fmaxf(v.y, 0.f), 1.f);
  r.z = fminf(fmaxf(v.z, 0.f), 1.f);
  return r;
}

// inverse-affine coefficients for ops 0..4 (rotate, shear_x, shear_y, trans_x, trans_y)
__device__ __forceinline__ void affine_params(int op, float s,
    float& a, float& b, float& tx, float& c, float& d, float& ty){
  a = 1.f; b = 0.f; tx = 0.f; c = 0.f; d = 1.f; ty = 0.f;
  if (op == 0){            // rotate by s*15deg: cos even, sin odd -> fold sign
    a = 0.96592582628907f; b = s * 0.25881904510252f; c = -b; d = a;
  } else if (op == 1){     // shear_x
    b = -s * 0.15f;
  } else if (op == 2){     // shear_y
    c = -s * 0.15f;
  } else if (op == 3){     // trans_x: t = s*0.15*512
    tx = -s * 76.8f;
  } else if (op == 4){     // trans_y
    ty = -s * 76.8f;
  }
}

// branchless bilinear: caller guarantees all 4 corners strictly in-image
__device__ __forceinline__ F3 bilin_interior(const float* __restrict__ im, float xi, float yi){
  float x0f = floorf(xi), y0f = floorf(yi);
  float wx = xi - x0f, wy = yi - y0f;
  float w00=(1.f-wx)*(1.f-wy), w01=wx*(1.f-wy), w10=(1.f-wx)*wy, w11=wx*wy;
  const float* p0 = im + ((int)y0f*IMW + (int)x0f)*3;
  const float* p1 = p0 + IMW*3;
  F3 r;
  r.x = w00*p0[0]+w01*p0[3]+w10*p1[0]+w11*p1[3];
  r.y = w00*p0[1]+w01*p0[4]+w10*p1[1]+w11*p1[4];
  r.z = w00*p0[2]+w01*p0[5]+w10*p1[2]+w11*p1[5];
  return r;
}

// general bilinear with FILL for out-of-bounds corners
__device__ __forceinline__ F3 bilin_img(const float* __restrict__ im, float xi, float yi){
  float x0f = floorf(xi), y0f = floorf(yi);
  float wx = xi - x0f, wy = yi - y0f;
  int x0 = (int)x0f, y0 = (int)y0f;
  F3 r;
  if (x0 >= 0 && y0 >= 0 && x0 < IMW-1 && y0 < IMH-1){
    return bilin_interior(im, xi, yi);
  }
  r = mk3(0.f);
  #pragma unroll
  for (int cidx = 0; cidx < 4; cidx++){
    int dx = cidx & 1, dy = cidx >> 1;
    int xx = x0 + dx, yy = y0 + dy;
    float w = (dx ? wx : (1.f - wx)) * (dy ? wy : (1.f - wy));
    F3 v;
    if (xx >= 0 && xx < IMW && yy >= 0 && yy < IMH)
      v = ldpix(im, yy, xx);
    else
      v = mk3(FILLF);
    r.x += w * v.x; r.y += w * v.y; r.z += w * v.z;
  }
  return r;
}

// value of the layer-0 output at integer pixel (x,y), computed on the fly
__device__ F3 eval0(const float* __restrict__ im, int op, float s, float mean0, int x, int y){
  if (op < 5){
    float a,b,tx,c,d,ty; affine_params(op, s, a, b, tx, c, d, ty);
    float fx = (float)x - CXF, fy = (float)y - CYF;
    return bilin_img(im, a*fx + b*fy + tx + CXF, c*fx + d*fy + ty + CYF);
  }
  F3 v = ldpix(im, y, x);
  float f = (s > 0.f) ? ENHF : INVENHF;
  if (op == 5){           // brightness: clip(f * img)
    F3 r; r.x = f*v.x; r.y = f*v.y; r.z = f*v.z; return clip01(r);
  }
  if (op == 6){           // contrast: clip(mean + f*(img-mean))
    F3 r;
    r.x = mean0 + f*(v.x - mean0);
    r.y = mean0 + f*(v.y - mean0);
    r.z = mean0 + f*(v.z - mean0);
    return clip01(r);
  }
  // sharpness: clip(smooth + f*(img - smooth)), 3x3 kernel [[1,1,1],[1,5,1],[1,1,1]]/13, edge pad
  F3 sm; sm.x = (5.f/13.f)*v.x; sm.y = (5.f/13.f)*v.y; sm.z = (5.f/13.f)*v.z;
  #pragma unroll
  for (int dy = -1; dy <= 1; dy++){
    #pragma unroll
    for (int dx = -1; dx <= 1; dx++){
      if (dx == 0 && dy == 0) continue;
      int yy = min(max(y + dy, 0), IMH-1);
      int xx = min(max(x + dx, 0), IMW-1);
      F3 q = ldpix(im, yy, xx);
      sm.x += (1.f/13.f)*q.x; sm.y += (1.f/13.f)*q.y; sm.z += (1.f/13.f)*q.z;
    }
  }
  F3 r;
  r.x = sm.x + f*(v.x - sm.x);
  r.y = sm.y + f*(v.y - sm.y);
  r.z = sm.z + f*(v.z - sm.z);
  return clip01(r);
}

__device__ __forceinline__ float block_reduce(float v){
  #pragma unroll
  for (int off = 32; off > 0; off >>= 1) v += __shfl_down(v, off, 64);
  __shared__ float sm[4];
  int lane = threadIdx.x & 63, wid = threadIdx.x >> 6;
  if (lane == 0) sm[wid] = v;
  __syncthreads();
  float r = 0.f;
  if (threadIdx.x == 0) r = sm[0] + sm[1] + sm[2] + sm[3];
  return r;
}

// mean of raw input image (only for images whose layer-0 op is contrast)
__global__ __launch_bounds__(256) void mean0_kernel(const float* __restrict__ images,
    const int* __restrict__ ops, float* __restrict__ means){
  int img = blockIdx.x / MBPI0;
  if (ops[2*img] != 6) return;
  const float4* im = (const float4*)(images + (size_t)img * NELEM);
  float s = 0.f;
  for (int i = (blockIdx.x % MBPI0)*256 + threadIdx.x; i < NELEM/4; i += MBPI0*256){
    float4 v = im[i];
    s += v.x + v.y + v.z + v.w;
  }
  s = block_reduce(s);
  if (threadIdx.x == 0) atomicAdd(&means[2*img], s * (1.0f/(float)NELEM));
}

// packed coalesced store: 4 px = 12 floats = 3 float4 (48B-aligned base)
__device__ __forceinline__ void store4(float* __restrict__ out, int img, int y, int xbase,
                                       const F3* res){
  float4 o0 = make_float4(res[0].x, res[0].y, res[0].z, res[1].x);
  float4 o1 = make_float4(res[1].y, res[1].z, res[2].x, res[2].y);
  float4 o2 = make_float4(res[2].z, res[3].x, res[3].y, res[3].z);
  float4* op = (float4*)(out + ((size_t)img * NPIX + (size_t)y * IMW + xbase) * 3);
  op[0] = o0; op[1] = o1; op[2] = o2;
}

// Tiled fused kernel, 32x32 tiles, tight-bbox LDS staging (20.4KB -> 8 blocks/CU).
// Block-uniform interior fast paths remove per-pixel branching in hot loops.
__global__ __launch_bounds__(256, 8) void apply_kernel(const float* __restrict__ images,
    const int* __restrict__ ops, const int* __restrict__ signs,
    float* __restrict__ means, float* __restrict__ out){
  int img  = blockIdx.x >> 8;            // 256 tiles per image (16 x 16)
  int tile = blockIdx.x & 255;
  int tx0 = (tile & 15) * TW;
  int ty0 = (tile >> 4) * TH;
  const float* im = images + (size_t)img * NELEM;
  int op0 = ops[2*img], op1 = ops[2*img + 1];
  float s0 = signs[2*img]     ? 1.f : -1.f;
  float s1 = signs[2*img + 1] ? 1.f : -1.f;
  float mean0 = means[2*img];

  int row   = threadIdx.x >> 3;                 // 0..31
  int xbase = tx0 + ((threadIdx.x & 7) << 2);   // 4 consecutive px per thread
  int y     = ty0 + row;
  float f1 = (s1 > 0.f) ? ENHF : INVENHF;

  // ---- pointwise layer-1: one eval0 per output px, no reuse -> no LDS round-trip ----
  if (op1 == 5 || op1 == 6){
    F3 v4[4];
    if (op0 < 5){
      float a0,b0,t0x,c0,d0,t0y; affine_params(op0, s0, a0,b0,t0x,c0,d0,t0y);
      // block-uniform interior test over output-tile corners
      float fxl = (float)tx0 - CXF, fxr = (float)(tx0+TW-1) - CXF;
      float fyt = (float)ty0 - CYF, fyb = (float)(ty0+TH-1) - CYF;
      float xA = a0*fxl + b0*fyt, xB = a0*fxr + b0*fyt, xC = a0*fxl + b0*fyb, xD = a0*fxr + b0*fyb;
      float yA = c0*fxl + d0*fyt, yB = c0*fxr + d0*fyt, yC = c0*fxl + d0*fyb, yD = c0*fxr + d0*fyb;
      float sxmin = fminf(fminf(xA,xB),fminf(xC,xD)) + t0x + CXF;
      float sxmax = fmaxf(fmaxf(xA,xB),fmaxf(xC,xD)) + t0x + CXF;
      float symin = fminf(fminf(yA,yB),fminf(yC,yD)) + t0y + CYF;
      float symax = fmaxf(fmaxf(yA,yB),fmaxf(yC,yD)) + t0y + CYF;
      bool inter = (sxmin >= 1.f) && (symin >= 1.f) &&
                   (sxmax <= (float)(IMW-2)) && (symax <= (float)(IMH-2));
      float fy = (float)y - CYF;
      if (inter){
        #pragma unroll
        for (int q = 0; q < 4; q++){
          float fx = (float)(xbase + q) - CXF;
          v4[q] = bilin_interior(im, a0*fx + b0*fy + t0x + CXF, c0*fx + d0*fy + t0y + CYF);
        }
      } else {
        #pragma unroll
        for (int q = 0; q < 4; q++){
          float fx = (float)(xbase + q) - CXF;
          v4[q] = bilin_img(im, a0*fx + b0*fy + t0x + CXF, c0*fx + d0*fy + t0y + CYF);
        }
      }
    } else {
      #pragma unroll
      for (int q = 0; q < 4; q++)
        v4[q] = eval0(im, op0, s0, mean0, xbase + q, y);
    }
    F3 res[4];
    float ssum = 0.f;
    #pragma unroll
    for (int q = 0; q < 4; q++){
      if (op1 == 5){
        F3 o; o.x = f1*v4[q].x; o.y = f1*v4[q].y; o.z = f1*v4[q].z;
        res[q] = clip01(o);
      } else {
        res[q] = v4[q];                   // write raw L0; fixup applies contrast
        ssum += v4[q].x + v4[q].y + v4[q].z;
      }
    }
    store4(out, img, y, xbase, res);
    if (op1 == 6){
      ssum = block_reduce(ssum);
      if (threadIdx.x == 0) atomicAdd(&means[2*img + 1], ssum * (1.0f/(float)NELEM));
    }
    return;
  }

  // ---- bbox of layer-0 pixels needed by this tile's layer-1 op (tight support) ----
  float a1=1.f,b1=0.f,txx=0.f,c1=0.f,d1=1.f,tyy=0.f;
  int pbx0, pby0, pbx1, pby1;            // pre-clamp
  if (op1 < 5){
    affine_params(op1, s1, a1, b1, txx, c1, d1, tyy);
    float xmin = 1e30f, xmax = -1e30f, ymin = 1e30f, ymax = -1e30f;
    #pragma unroll
    for (int i = 0; i < 4; i++){
      float fx = (float)(tx0 + (i & 1) * (TW - 1)) - CXF;
      float fy = (float)(ty0 + (i >> 1) * (TH - 1)) - CYF;
      float xi = a1*fx + b1*fy + txx + CXF;
      float yi = c1*fx + d1*fy + tyy + CYF;
      xmin = fminf(xmin, xi); xmax = fmaxf(xmax, xi);
      ymin = fminf(ymin, yi); ymax = fmaxf(ymax, yi);
    }
    pbx0 = (int)floorf(xmin); pbx1 = (int)floorf(xmax) + 1;
    pby0 = (int)floorf(ymin); pby1 = (int)floorf(ymax) + 1;
  } else {                               // sharpness needs +-1 halo
    pbx0 = tx0 - 1; pbx1 = tx0 + TW; pby0 = ty0 - 1; pby1 = ty0 + TH;
  }
  int bx0 = max(pbx0, 0), by0 = max(pby0, 0);
  int bx1 = min(pbx1, IMW - 1), by1 = min(pby1, IMH - 1);
  int bw = bx1 - bx0 + 1, bh = by1 - by0 + 1;
  int nstage = (bw > 0 && bh > 0) ? bw * bh : 0;
  bool l1_interior = (op1 < 5) && pbx0 >= 0 && pby0 >= 0 && pbx1 <= IMW-1 && pby1 <= IMH-1;

  // ---- stage eval0 over bbox into LDS (each layer-0 pixel computed ONCE) ----
  __shared__ float lds[MAXLDS * 3];
  if (nstage > 0){
    int Kq = 256 / bw, Rr = 256 - Kq * bw;
    int iy = (int)threadIdx.x / bw;
    int ix = (int)threadIdx.x - iy * bw;
    if (op0 < 5){
      float a0,b0,t0x,c0,d0,t0y; affine_params(op0, s0, a0,b0,t0x,c0,d0,t0y);
      float Cx = a0*((float)bx0 - CXF) + b0*((float)by0 - CYF) + t0x + CXF;
      float Cy = c0*((float)bx0 - CXF) + d0*((float)by0 - CYF) + t0y + CYF;
      // block-uniform interior test over staged-bbox corners (0.5px+ safety margin)
      float w = (float)(bw - 1), h = (float)(bh - 1);
      float x00 = Cx, x10 = Cx + a0*w, x01 = Cx + b0*h, x11 = Cx + a0*w + b0*h;
      float y00 = Cy, y10 = Cy + c0*w, y01 = Cy + d0*h, y11 = Cy + c0*w + d0*h;
      float sxmin = fminf(fminf(x00,x10),fminf(x01,x11));
      float sxmax = fmaxf(fmaxf(x00,x10),fmaxf(x01,x11));
      float symin = fminf(fminf(y00,y10),fminf(y01,y11));
      float symax = fmaxf(fmaxf(y00,y10),fmaxf(y01,y11));
      bool inter = (sxmin >= 1.f) && (symin >= 1.f) &&
                   (sxmax <= (float)(IMW-2)) && (symax <= (float)(IMH-2));
      if (inter){
        for (int idx = threadIdx.x; idx < nstage; idx += 256){
          float xi = a0*(float)ix + b0*(float)iy + Cx;
          float yi = c0*(float)ix + d0*(float)iy + Cy;
          F3 v = bilin_interior(im, xi, yi);
          lds[idx*3+0]=v.x; lds[idx*3+1]=v.y; lds[idx*3+2]=v.z;
          ix += Rr; iy += Kq; if (ix >= bw){ ix -= bw; iy += 1; }
        }
      } else {
        for (int idx = threadIdx.x; idx < nstage; idx += 256){
          float xi = a0*(float)ix + b0*(float)iy + Cx;
          float yi = c0*(float)ix + d0*(float)iy + Cy;
          F3 v = bilin_img(im, xi, yi);
          lds[idx*3+0]=v.x; lds[idx*3+1]=v.y; lds[idx*3+2]=v.z;
          ix += Rr; iy += Kq; if (ix >= bw){ ix -= bw; iy += 1; }
        }
      }
    } else {
      for (int idx = threadIdx.x; idx < nstage; idx += 256){
        F3 v = eval0(im, op0, s0, mean0, bx0 + ix, by0 + iy);
        lds[idx*3+0]=v.x; lds[idx*3+1]=v.y; lds[idx*3+2]=v.z;
        ix += Rr; iy += Kq; if (ix >= bw){ ix -= bw; iy += 1; }
      }
    }
  }
  __syncthreads();

  // ---- layer-1 from LDS ----
  F3 res[4];
  if (op1 < 5 && l1_interior){
    // branchless: all corners in-image and staged; ulp-safe via index clamping
    float fy = (float)y - CYF;
    #pragma unroll
    for (int q = 0; q < 4; q++){
      float fx = (float)(xbase + q) - CXF;
      float xi = a1*fx + b1*fy + txx + CXF;
      float yi = c1*fx + d1*fy + tyy + CYF;
      float x0f = fminf(fmaxf(floorf(xi), (float)bx0), (float)(bx1-1));
      float y0f = fminf(fmaxf(floorf(yi), (float)by0), (float)(by1-1));
      float wx = xi - x0f, wy = yi - y0f;
      float w00=(1.f-wx)*(1.f-wy), w01=wx*(1.f-wy), w10=(1.f-wx)*wy, w11=wx*wy;
      const float* q0 = lds + (((int)y0f - by0) * bw + ((int)x0f - bx0)) * 3;
      const float* q1 = q0 + bw * 3;
      F3 o;
      o.x = w00*q0[0] + w01*q0[3] + w10*q1[0] + w11*q1[3];
      o.y = w00*q0[1] + w01*q0[4] + w10*q1[1] + w11*q1[4];
      o.z = w00*q0[2] + w01*q0[5] + w10*q1[2] + w11*q1[5];
      res[q] = clip01(o);
    }
  } else {
    #pragma unroll
    for (int q = 0; q < 4; q++){
      int x = xbase + q;
      F3 o;
      if (op1 < 5){
        float fx = (float)x - CXF, fy = (float)y - CYF;
        float xi = a1*fx + b1*fy + txx + CXF;
        float yi = c1*fx + d1*fy + tyy + CYF;
        float xf0 = floorf(xi), yf0 = floorf(yi);
        float wx = xi - xf0, wy = yi - yf0;
        int x0 = (int)xf0, y0 = (int)yf0;
        o = mk3(0.f);
        #pragma unroll
        for (int ci = 0; ci < 4; ci++){
          int dx = ci & 1, dy = ci >> 1;
          int xx = x0 + dx, yy = y0 + dy;
          float wq = (dx ? wx : (1.f - wx)) * (dy ? wy : (1.f - wy));
          F3 v;
          if (xx >= 0 && xx < IMW && yy >= 0 && yy < IMH){
            int lx = min(max(xx - bx0, 0), bw - 1);
            int ly = min(max(yy - by0, 0), bh - 1);
            int li = (ly * bw + lx) * 3;
            v.x = lds[li]; v.y = lds[li+1]; v.z = lds[li+2];
          } else v = mk3(FILLF);
          o.x += wq * v.x; o.y += wq * v.y; o.z += wq * v.z;
        }
      } else {  // sharpness over layer-0 output, taps from LDS (edge-clamped)
        int li0 = ((y - by0) * bw + (x - bx0)) * 3;
        F3 v; v.x = lds[li0]; v.y = lds[li0+1]; v.z = lds[li0+2];
        F3 sm; sm.x = (5.f/13.f)*v.x; sm.y = (5.f/13.f)*v.y; sm.z = (5.f/13.f)*v.z;
        #pragma unroll
        for (int dy = -1; dy <= 1; dy++){
          #pragma unroll
          for (int dx = -1; dx <= 1; dx++){
            if (dx == 0 && dy == 0) continue;
            int yy = min(max(y + dy, 0), IMH-1);
            int xx = min(max(x + dx, 0), IMW-1);
            int li = ((yy - by0) * bw + (xx - bx0)) * 3;
            sm.x += (1.f/13.f)*lds[li];
            sm.y += (1.f/13.f)*lds[li+1];
            sm.z += (1.f/13.f)*lds[li+2];
          }
        }
        o.x = sm.x + f1*(v.x - sm.x);
        o.y = sm.y + f1*(v.y - sm.y);
        o.z = sm.z + f1*(v.z - sm.z);
      }
      res[q] = clip01(o);
    }
  }

  store4(out, img, y, xbase, res);
}

// In-place contrast finish for images with op1==6: out = clip(m1 + f*(L0 - m1)).
__global__ __launch_bounds__(256) void fixup_kernel(const int* __restrict__ ops,
    const int* __restrict__ signs, const float* __restrict__ means,
    float* __restrict__ out){
  int img = blockIdx.x >> 8;             // 256 blocks per image
  if (ops[2*img + 1] != 6) return;
  float f = signs[2*img + 1] ? ENHF : INVENHF;
  float m = means[2*img + 1];
  float4* p = (float4*)(out + (size_t)img * NELEM);
  const int n = NELEM / 4;               // 196608
  for (int i = (blockIdx.x & 255)*256 + threadIdx.x; i < n; i += 256*256){
    float4 v = p[i];
    v.x = fminf(fmaxf(m + f*(v.x - m), 0.f), 1.f);
    v.y = fminf(fmaxf(m + f*(v.y - m), 0.f), 1.f);
    v.z = fminf(fmaxf(m + f*(v.z - m), 0.f), 1.f);
    v.w = fminf(fmaxf(m + f*(v.w - m), 0.f), 1.f);
    p[i] = v;
  }
}

extern "C" void kernel_launch(void* const* d_in, const int* in_sizes, int n_in,
                              void* d_out, int out_size, void* d_ws, size_t ws_size,
                              hipStream_t stream){
  const float* images = (const float*)d_in[0];
  const int*   ops    = (const int*)d_in[1];
  const int*   signs  = (const int*)d_in[2];
  float* out   = (float*)d_out;
  float* means = (float*)d_ws;   // 2 floats per image: [mean0, mean1]

  hipMemsetAsync(means, 0, 2*NIMG*sizeof(float), stream);
  mean0_kernel<<<NIMG*MBPI0, 256, 0, stream>>>(images, ops, means);
  apply_kernel<<<NIMG*256, 256, 0, stream>>>(images, ops, signs, means, out);
  fixup_kernel<<<NIMG*256, 256, 0, stream>>>(ops, signs, means, out);
}